// Round 1
// baseline (6012.358 us; speedup 1.0000x reference)
//
#include <hip/hip_runtime.h>

#define RPB 16   // pairs (rows) per block
#define CK  16   // Cin chunk

// Generic row-gather GEMM with optional scatter.
//   mode accum=0: Out[p] = X[p] @ W              (im/om null, p in [0,P))
//   mode accum=1: Out[om[p]] += X[im[p]] @ W     (skip if om[p] >= nOut)
// blockDim.x == Cout (64 or 128). Cin % CK == 0.
__global__ void gemm_tap(const float* __restrict__ X, const float* __restrict__ W,
                         float* __restrict__ Out,
                         const int* __restrict__ im, const int* __restrict__ om,
                         int P, int Cin, int Cout, int nOut, int accum)
{
    __shared__ float Xl[RPB * CK];
    __shared__ int   rin[RPB];
    __shared__ int   rout[RPB];
    __shared__ int   anyv;

    const int t = threadIdx.x;                  // t in [0, Cout)
    const long base = (long)blockIdx.x * RPB;

    if (t < RPB) {
        long p = base + t;
        int ri = -1, ro = -1;
        if (p < (long)P) {
            ri = im ? im[p] : (int)p;
            ro = om ? om[p] : (int)p;
            if (ro >= nOut) { ri = -1; ro = -1; }   // padded scrap entry
        }
        rin[t]  = ri;
        rout[t] = ro;
    }
    __syncthreads();
    if (t == 0) {
        int a = 0;
        #pragma unroll
        for (int r = 0; r < RPB; r++) a |= (rout[r] >= 0) ? 1 : 0;
        anyv = a;
    }
    __syncthreads();
    if (!anyv) return;                          // fully-padded tail block

    float acc[RPB];
    #pragma unroll
    for (int r = 0; r < RPB; r++) acc[r] = 0.f;

    for (int c0 = 0; c0 < Cin; c0 += CK) {
        // stage X chunk: RPB rows x CK channels
        for (int e = t; e < RPB * CK; e += blockDim.x) {
            int r = e >> 4;                     // e / CK
            int i = e & (CK - 1);
            int row = rin[r];
            Xl[e] = (row >= 0) ? X[(long)row * Cin + c0 + i] : 0.f;
        }
        __syncthreads();
        // W chunk straight to registers (coalesced, L1/L2-resident across blocks)
        float wreg[CK];
        #pragma unroll
        for (int i = 0; i < CK; i++) wreg[i] = W[(long)(c0 + i) * Cout + t];
        #pragma unroll
        for (int r = 0; r < RPB; r++) {
            float a0 = 0.f;
            #pragma unroll
            for (int i = 0; i < CK; i++) a0 += Xl[r * CK + i] * wreg[i];
            acc[r] += a0;
        }
        __syncthreads();
    }

    #pragma unroll
    for (int r = 0; r < RPB; r++) {
        int ro = rout[r];
        if (ro >= 0) {
            long o = (long)ro * Cout + t;
            if (accum) Out[o] += acc[r];
            else       Out[o] = acc[r];
        }
    }
}

// dst[idx[r]] += src[r]  (idx injective within one launch)
__global__ void scatter_add_k(float* __restrict__ dst, const float* __restrict__ src,
                              const int* __restrict__ idx, long total, int C)
{
    long tid = (long)blockIdx.x * blockDim.x + threadIdx.x;
    if (tid >= total) return;
    long r = tid / C;
    int  c = (int)(tid - r * C);
    dst[(long)idx[r] * C + c] += src[tid];
}

// per-channel sum / sumsq -> stats[0:C], stats[C:2C]. blockDim = 256, C in {64,128}.
__global__ void bn_stats_k(const float* __restrict__ X, float* __restrict__ stats,
                           int n, int C, int rowsPerBlock)
{
    const int t   = threadIdx.x;
    const int c   = t & (C - 1);
    const int sub = t / C;
    const int nsub = 256 / C;
    int r0 = blockIdx.x * rowsPerBlock + sub;
    int r1 = blockIdx.x * rowsPerBlock + rowsPerBlock;
    if (r1 > n) r1 = n;
    float s = 0.f, ss = 0.f;
    for (int r = r0; r < r1; r += nsub) {
        float v = X[(long)r * C + c];
        s += v; ss += v * v;
    }
    __shared__ float bs[256];
    __shared__ float bq[256];
    bs[t] = s; bq[t] = ss;
    __syncthreads();
    if (sub == 0) {
        for (int k = 1; k < nsub; k++) { s += bs[k * C + c]; ss += bq[k * C + c]; }
        atomicAdd(&stats[c], s);
        atomicAdd(&stats[C + c], ss);
    }
}

// x = elu(g * (x-mu) * rsqrt(var+eps) + b), in place. gb = [gamma(C); beta(C)]
__global__ void bn_apply_k(float* __restrict__ X, const float* __restrict__ stats,
                           const float* __restrict__ gb, long total, int C, float invn)
{
    long tid = (long)blockIdx.x * blockDim.x + threadIdx.x;
    if (tid >= total) return;
    int c = (int)(tid & (C - 1));
    float mu  = stats[c] * invn;
    float var = stats[C + c] * invn - mu * mu;
    float sc  = gb[c] * rsqrtf(var + 1e-5f);
    float v   = (X[tid] - mu) * sc + gb[C + c];
    X[tid] = (v > 0.f) ? v : expm1f(v);
}

extern "C" void kernel_launch(void* const* d_in, const int* in_sizes, int n_in,
                              void* d_out, int out_size, void* d_ws, size_t ws_size,
                              hipStream_t stream)
{
    const float* feats0  = (const float*)d_in[0];
    const float* feats1  = (const float*)d_in[1];
    const float* feats2  = (const float*)d_in[2];
    const float* w_out0  = (const float*)d_in[3];
    const float* w_out1  = (const float*)d_in[4];
    const float* w_out2  = (const float*)d_in[5];
    const float* wt2     = (const float*)d_in[6];
    const float* wu2     = (const float*)d_in[7];
    const float* wt1     = (const float*)d_in[8];
    const float* wu1     = (const float*)d_in[9];
    const float* bn_out0 = (const float*)d_in[10];
    const float* bn_out1 = (const float*)d_in[11];
    const float* bn_out2 = (const float*)d_in[12];
    const float* bn_up2a = (const float*)d_in[13];
    const float* bn_up2b = (const float*)d_in[14];
    const float* bn_up1a = (const float*)d_in[15];
    const float* bn_up1b = (const float*)d_in[16];
    const int* m_c2 = (const int*)d_in[19];
    const int* m_g2 = (const int*)d_in[20];
    const int* m_u1 = (const int*)d_in[21];
    const int* m_g1 = (const int*)d_in[22];
    const int* m_u0 = (const int*)d_in[23];
    const int* lat1 = (const int*)d_in[24];
    const int* up1  = (const int*)d_in[25];
    const int* lat0 = (const int*)d_in[26];
    const int* up0  = (const int*)d_in[27];

    const int N0  = in_sizes[0] / 64;    // 16000
    const int N1  = in_sizes[1] / 128;   // 6000
    const int N2  = in_sizes[2] / 256;   // 1200
    const int U1  = in_sizes[17] / 128;
    const int U0  = in_sizes[18] / 64;
    const int G2n = in_sizes[25];        // 8*N2 = 9600
    const int G1n = in_sizes[27];        // 8*U1
    const int Mc2 = in_sizes[19] / 52;
    const int Mg2 = in_sizes[20] / 52;
    const int Mu1 = in_sizes[21] / 52;
    const int Mg1 = in_sizes[22] / 52;
    const int Mu0 = in_sizes[23] / 52;

    float* out0 = (float*)d_out;
    float* out1 = out0 + (size_t)U0 * 128;
    float* out2 = out1 + (size_t)U1 * 128;

    float* ws    = (float*)d_ws;
    float* t2    = ws; ws += (size_t)G2n * 128;
    float* t2c   = ws; ws += (size_t)G2n * 128;
    float* x1    = ws; ws += (size_t)U1 * 128;
    float* t1    = ws; ws += (size_t)G1n * 64;
    float* t1c   = ws; ws += (size_t)G1n * 64;
    float* x0    = ws; ws += (size_t)U0 * 64;
    float* stats = ws; ws += 256;

    auto conv = [&](const float* X, const float* W27, const int* map, int M,
                    int n, int Cin, int Cout, float* Out) {
        // center tap initializes Out
        gemm_tap<<<dim3((n + RPB - 1) / RPB), dim3(Cout), 0, stream>>>(
            X, W27 + (size_t)13 * Cin * Cout, Out, nullptr, nullptr, n, Cin, Cout, n, 0);
        // 26 non-center taps, sequential launches (race-free within a tap)
        for (int j = 0; j < 26; j++) {
            int k = (j < 13) ? j : j + 1;
            gemm_tap<<<dim3((M + RPB - 1) / RPB), dim3(Cout), 0, stream>>>(
                X, W27 + (size_t)k * Cin * Cout, Out,
                map + (size_t)j * M, map + (size_t)(26 + j) * M, M, Cin, Cout, n, 1);
        }
    };

    auto tconv = [&](const float* X, const float* Wt, float* Out, int n, int C, int D) {
        for (int o = 0; o < 8; o++) {
            gemm_tap<<<dim3((n + RPB - 1) / RPB), dim3(D), 0, stream>>>(
                X, Wt + (size_t)o * C * D, Out + (size_t)o * n * D,
                nullptr, nullptr, n, C, D, n, 0);
        }
    };

    auto bnelu = [&](float* X, const float* gb, int n, int C) {
        hipMemsetAsync(stats, 0, 2 * C * sizeof(float), stream);
        const int rpb = 512;
        bn_stats_k<<<dim3((n + rpb - 1) / rpb), dim3(256), 0, stream>>>(X, stats, n, C, rpb);
        long total = (long)n * C;
        bn_apply_k<<<dim3((int)((total + 255) / 256)), dim3(256), 0, stream>>>(
            X, stats, gb, total, C, 1.0f / (float)n);
    };

    auto scat = [&](float* dst, const float* src, const int* idx, int rows, int C) {
        long total = (long)rows * C;
        scatter_add_k<<<dim3((int)((total + 255) / 256)), dim3(256), 0, stream>>>(
            dst, src, idx, total, C);
    };

    // ---- level 2 ----
    conv(feats2, w_out2, m_c2, Mc2, N2, 256, 128, out2);
    bnelu(out2, bn_out2, N2, 128);
    tconv(feats2, wt2, t2, N2, 256, 128);
    bnelu(t2, bn_up2a, G2n, 128);
    conv(t2, wu2, m_g2, Mg2, G2n, 128, 128, t2c);
    bnelu(t2c, bn_up2b, G2n, 128);

    // ---- level 1 assemble: x1 = scatter(feats1) + scatter(t2c) ----
    hipMemsetAsync(x1, 0, (size_t)U1 * 128 * sizeof(float), stream);
    scat(x1, feats1, lat1, N1, 128);
    scat(x1, t2c, up1, G2n, 128);

    conv(x1, w_out1, m_u1, Mu1, U1, 128, 128, out1);
    bnelu(out1, bn_out1, U1, 128);
    tconv(x1, wt1, t1, U1, 128, 64);
    bnelu(t1, bn_up1a, G1n, 64);
    conv(t1, wu1, m_g1, Mg1, G1n, 64, 64, t1c);
    bnelu(t1c, bn_up1b, G1n, 64);

    // ---- level 0 assemble: x0 = scatter(feats0) + scatter(t1c) ----
    hipMemsetAsync(x0, 0, (size_t)U0 * 64 * sizeof(float), stream);
    scat(x0, feats0, lat0, N0, 64);
    scat(x0, t1c, up0, G1n, 64);

    conv(x0, w_out0, m_u0, Mu0, U0, 64, 128, out0);
    bnelu(out0, bn_out0, U0, 128);
}

// Round 2
// 2989.846 us; speedup vs baseline: 2.0109x; 2.0109x over previous
//
#include <hip/hip_runtime.h>

#define RPB 16   // output rows per block
#define CK  16   // Cin chunk held in registers

// ---------------- tap table build ----------------
// tab[r*27 + j] = input row feeding output r via tap j, or -1. Center (13) = r.
__global__ void table_init(int* __restrict__ tab, int n)
{
    int idx = blockIdx.x * blockDim.x + threadIdx.x;
    if (idx >= n * 27) return;
    tab[idx] = ((idx % 27) == 13) ? (idx / 27) : -1;
}

// map layout [2][26][M]: plane0 = im (gather rows), plane1 = om (scatter rows, ==n for pad)
__global__ void table_fill(int* __restrict__ tab, const int* __restrict__ map, int M, int n)
{
    int tid = blockIdx.x * blockDim.x + threadIdx.x;
    if (tid >= 26 * M) return;
    int j = tid / M, q = tid - j * M;
    int om = map[(26 + j) * M + q];
    if (om < n) {
        int k = (j < 13) ? j : j + 1;          // skip center in tap numbering
        tab[om * 27 + k] = map[j * M + q];
    }
}

// ---------------- output-centric sparse conv ----------------
// One block: RPB output rows. 128 threads = 2 waves; wave w handles rows [w*8, w*8+8).
// COPT couts per thread (Cout = 64*COPT). Writes Out exactly once.
template<int COPT>
__global__ void conv_all(const float* __restrict__ X, const float* __restrict__ W27,
                         const int* __restrict__ tab, float* __restrict__ Out,
                         int n, int Cin, int cinShift)
{
    const int Cout = 64 * COPT;
    extern __shared__ float sm[];
    float* Xl  = sm;                          // RPB * Cin
    int*   tps = (int*)(sm + RPB * Cin);      // RPB * 27

    const int t = threadIdx.x, lane = t & 63, wv = t >> 6;
    const int r0 = blockIdx.x * RPB;
    int rows = n - r0; if (rows > RPB) rows = RPB;

    for (int e = t; e < rows * 27; e += 128) tps[e] = tab[r0 * 27 + e];

    float acc[8][COPT];
    #pragma unroll
    for (int r = 0; r < 8; r++)
        #pragma unroll
        for (int p = 0; p < COPT; p++) acc[r][p] = 0.f;

    __syncthreads();

    for (int j = 0; j < 27; j++) {
        // block-uniform any-valid check (taps identical for all threads)
        bool any = false;
        for (int r = 0; r < rows; r++) any |= (tps[r * 27 + j] >= 0);
        if (!any) continue;

        __syncthreads();                       // Xl reuse vs previous tap's reads
        for (int e = t; e < (rows << cinShift); e += 128) {
            int r = e >> cinShift, c = e & (Cin - 1);
            int in = tps[r * 27 + j];
            if (in >= 0) Xl[e] = X[(size_t)in * Cin + c];
        }
        __syncthreads();

        const float* Wj = W27 + (size_t)j * Cin * Cout;
        for (int c0 = 0; c0 < Cin; c0 += CK) {
            float wreg[CK][COPT];
            #pragma unroll
            for (int i = 0; i < CK; i++)
                #pragma unroll
                for (int p = 0; p < COPT; p++)
                    wreg[i][p] = Wj[(size_t)(c0 + i) * Cout + p * 64 + lane];
            #pragma unroll
            for (int r8 = 0; r8 < 8; r8++) {
                int r = wv * 8 + r8;
                if (r < rows && tps[r * 27 + j] >= 0) {
                    const float* xp = Xl + (r << cinShift) + c0;
                    #pragma unroll
                    for (int i = 0; i < CK; i += 4) {
                        float4 xv = *(const float4*)(xp + i);
                        #pragma unroll
                        for (int p = 0; p < COPT; p++) {
                            acc[r8][p] += xv.x * wreg[i    ][p];
                            acc[r8][p] += xv.y * wreg[i + 1][p];
                            acc[r8][p] += xv.z * wreg[i + 2][p];
                            acc[r8][p] += xv.w * wreg[i + 3][p];
                        }
                    }
                }
            }
        }
    }

    #pragma unroll
    for (int r8 = 0; r8 < 8; r8++) {
        int r = wv * 8 + r8;
        if (r < rows)
            #pragma unroll
            for (int p = 0; p < COPT; p++)
                Out[(size_t)(r0 + r) * Cout + p * 64 + lane] = acc[r8][p];
    }
}

// ---------------- transpose conv: all 8 children, X staged once ----------------
template<int COPT>
__global__ void tconv_all(const float* __restrict__ X, const float* __restrict__ Wt,
                          float* __restrict__ Out, int n, int Cin, int cinShift)
{
    const int Cout = 64 * COPT;
    extern __shared__ float sm[];
    float* Xl = sm;                           // RPB * Cin

    const int t = threadIdx.x, lane = t & 63, wv = t >> 6;
    const int r0 = blockIdx.x * RPB;
    int rows = n - r0; if (rows > RPB) rows = RPB;

    for (int e = t; e < (rows << cinShift); e += 128) {
        int r = e >> cinShift, c = e & (Cin - 1);
        Xl[e] = X[(size_t)(r0 + r) * Cin + c];
    }
    __syncthreads();

    for (int o = 0; o < 8; o++) {
        float acc[8][COPT];
        #pragma unroll
        for (int r = 0; r < 8; r++)
            #pragma unroll
            for (int p = 0; p < COPT; p++) acc[r][p] = 0.f;

        const float* Wo = Wt + (size_t)o * Cin * Cout;
        for (int c0 = 0; c0 < Cin; c0 += CK) {
            float wreg[CK][COPT];
            #pragma unroll
            for (int i = 0; i < CK; i++)
                #pragma unroll
                for (int p = 0; p < COPT; p++)
                    wreg[i][p] = Wo[(size_t)(c0 + i) * Cout + p * 64 + lane];
            #pragma unroll
            for (int r8 = 0; r8 < 8; r8++) {
                int r = wv * 8 + r8;
                if (r < rows) {
                    const float* xp = Xl + (r << cinShift) + c0;
                    #pragma unroll
                    for (int i = 0; i < CK; i += 4) {
                        float4 xv = *(const float4*)(xp + i);
                        #pragma unroll
                        for (int p = 0; p < COPT; p++) {
                            acc[r8][p] += xv.x * wreg[i    ][p];
                            acc[r8][p] += xv.y * wreg[i + 1][p];
                            acc[r8][p] += xv.z * wreg[i + 2][p];
                            acc[r8][p] += xv.w * wreg[i + 3][p];
                        }
                    }
                }
            }
        }
        #pragma unroll
        for (int r8 = 0; r8 < 8; r8++) {
            int r = wv * 8 + r8;
            if (r < rows)
                #pragma unroll
                for (int p = 0; p < COPT; p++)
                    Out[(size_t)((size_t)o * n + r0 + r) * Cout + p * 64 + lane] = acc[r8][p];
        }
    }
}

// ---------------- misc ----------------
__global__ void scatter_add_k(float* __restrict__ dst, const float* __restrict__ src,
                              const int* __restrict__ idx, long total, int C)
{
    long tid = (long)blockIdx.x * blockDim.x + threadIdx.x;
    if (tid >= total) return;
    long r = tid / C;
    int  c = (int)(tid - r * C);
    dst[(long)idx[r] * C + c] += src[tid];
}

__global__ void bn_stats_k(const float* __restrict__ X, float* __restrict__ stats,
                           int n, int C, int rowsPerBlock)
{
    const int t = threadIdx.x;
    const int c = t & (C - 1);
    const int sub = t / C;
    const int nsub = 256 / C;
    int r0 = blockIdx.x * rowsPerBlock + sub;
    int r1 = blockIdx.x * rowsPerBlock + rowsPerBlock;
    if (r1 > n) r1 = n;
    float s = 0.f, ss = 0.f;
    for (int r = r0; r < r1; r += nsub) {
        float v = X[(long)r * C + c];
        s += v; ss += v * v;
    }
    __shared__ float bs[256];
    __shared__ float bq[256];
    bs[t] = s; bq[t] = ss;
    __syncthreads();
    if (sub == 0) {
        for (int k = 1; k < nsub; k++) { s += bs[k * C + c]; ss += bq[k * C + c]; }
        atomicAdd(&stats[c], s);
        atomicAdd(&stats[C + c], ss);
    }
}

__global__ void bn_apply_k(float* __restrict__ X, const float* __restrict__ stats,
                           const float* __restrict__ gb, long total, int C, float invn)
{
    long tid = (long)blockIdx.x * blockDim.x + threadIdx.x;
    if (tid >= total) return;
    int c = (int)(tid & (C - 1));
    float mu  = stats[c] * invn;
    float var = stats[C + c] * invn - mu * mu;
    float sc  = gb[c] * rsqrtf(var + 1e-5f);
    float v   = (X[tid] - mu) * sc + gb[C + c];
    X[tid] = (v > 0.f) ? v : expm1f(v);
}

extern "C" void kernel_launch(void* const* d_in, const int* in_sizes, int n_in,
                              void* d_out, int out_size, void* d_ws, size_t ws_size,
                              hipStream_t stream)
{
    const float* feats0  = (const float*)d_in[0];
    const float* feats1  = (const float*)d_in[1];
    const float* feats2  = (const float*)d_in[2];
    const float* w_out0  = (const float*)d_in[3];
    const float* w_out1  = (const float*)d_in[4];
    const float* w_out2  = (const float*)d_in[5];
    const float* wt2     = (const float*)d_in[6];
    const float* wu2     = (const float*)d_in[7];
    const float* wt1     = (const float*)d_in[8];
    const float* wu1     = (const float*)d_in[9];
    const float* bn_out0 = (const float*)d_in[10];
    const float* bn_out1 = (const float*)d_in[11];
    const float* bn_out2 = (const float*)d_in[12];
    const float* bn_up2a = (const float*)d_in[13];
    const float* bn_up2b = (const float*)d_in[14];
    const float* bn_up1a = (const float*)d_in[15];
    const float* bn_up1b = (const float*)d_in[16];
    const int* m_c2 = (const int*)d_in[19];
    const int* m_g2 = (const int*)d_in[20];
    const int* m_u1 = (const int*)d_in[21];
    const int* m_g1 = (const int*)d_in[22];
    const int* m_u0 = (const int*)d_in[23];
    const int* lat1 = (const int*)d_in[24];
    const int* up1  = (const int*)d_in[25];
    const int* lat0 = (const int*)d_in[26];
    const int* up0  = (const int*)d_in[27];

    const int N0  = in_sizes[0] / 64;
    const int N1  = in_sizes[1] / 128;
    const int N2  = in_sizes[2] / 256;
    const int U1  = in_sizes[17] / 128;
    const int U0  = in_sizes[18] / 64;
    const int G2n = in_sizes[25];        // 8*N2
    const int G1n = in_sizes[27];        // 8*U1
    const int Mc2 = in_sizes[19] / 52;
    const int Mg2 = in_sizes[20] / 52;
    const int Mu1 = in_sizes[21] / 52;
    const int Mg1 = in_sizes[22] / 52;
    const int Mu0 = in_sizes[23] / 52;

    float* out0 = (float*)d_out;
    float* out1 = out0 + (size_t)U0 * 128;
    float* out2 = out1 + (size_t)U1 * 128;

    // workspace layout (floats); big tap tables overlap dead regions:
    //   g1 table over [t2|t2c|x1] (dead by then), u0 table over [t1] (dead by then)
    float* ws   = (float*)d_ws;
    float* t2   = ws;                    // G2n*128
    float* t2c  = t2  + (size_t)G2n * 128;
    float* x1   = t2c + (size_t)G2n * 128;
    float* t1   = x1  + (size_t)U1  * 128;
    float* t1c  = t1  + (size_t)G1n * 64;
    float* x0   = t1c + (size_t)G1n * 64;
    float* stats= x0  + (size_t)U0  * 64;
    int*  smallTab = (int*)(stats + 256);          // up to U1*27 ints
    int*  tab_g1   = (int*)t2;                      // G1n*27 ints <= t2+t2c+x1 bytes
    int*  tab_u0   = (int*)t1;                      // U0*27 ints <= t1 bytes

    auto conv = [&](const float* X, const float* W27, const int* map, int M,
                    int n, int Cin, int cinShift, int Cout, int* tab, float* Out) {
        int tot = n * 27;
        table_init<<<dim3((tot + 255) / 256), dim3(256), 0, stream>>>(tab, n);
        int tot2 = 26 * M;
        table_fill<<<dim3((tot2 + 255) / 256), dim3(256), 0, stream>>>(tab, map, M, n);
        size_t lds = (size_t)RPB * Cin * 4 + RPB * 27 * 4;
        int blocks = (n + RPB - 1) / RPB;
        if (Cout == 128)
            conv_all<2><<<dim3(blocks), dim3(128), lds, stream>>>(X, W27, tab, Out, n, Cin, cinShift);
        else
            conv_all<1><<<dim3(blocks), dim3(128), lds, stream>>>(X, W27, tab, Out, n, Cin, cinShift);
    };

    auto tconv = [&](const float* X, const float* Wt, float* Out, int n,
                     int Cin, int cinShift, int Cout) {
        size_t lds = (size_t)RPB * Cin * 4;
        int blocks = (n + RPB - 1) / RPB;
        if (Cout == 128)
            tconv_all<2><<<dim3(blocks), dim3(128), lds, stream>>>(X, Wt, Out, n, Cin, cinShift);
        else
            tconv_all<1><<<dim3(blocks), dim3(128), lds, stream>>>(X, Wt, Out, n, Cin, cinShift);
    };

    auto bnelu = [&](float* X, const float* gb, int n, int C) {
        hipMemsetAsync(stats, 0, 2 * C * sizeof(float), stream);
        const int rpb = 512;
        bn_stats_k<<<dim3((n + rpb - 1) / rpb), dim3(256), 0, stream>>>(X, stats, n, C, rpb);
        long total = (long)n * C;
        bn_apply_k<<<dim3((int)((total + 255) / 256)), dim3(256), 0, stream>>>(
            X, stats, gb, total, C, 1.0f / (float)n);
    };

    auto scat = [&](float* dst, const float* src, const int* idx, int rows, int C) {
        long total = (long)rows * C;
        scatter_add_k<<<dim3((int)((total + 255) / 256)), dim3(256), 0, stream>>>(
            dst, src, idx, total, C);
    };

    // ---- level 2 ----
    conv(feats2, w_out2, m_c2, Mc2, N2, 256, 8, 128, smallTab, out2);
    bnelu(out2, bn_out2, N2, 128);
    tconv(feats2, wt2, t2, N2, 256, 8, 128);
    bnelu(t2, bn_up2a, G2n, 128);
    conv(t2, wu2, m_g2, Mg2, G2n, 128, 7, 128, smallTab, t2c);
    bnelu(t2c, bn_up2b, G2n, 128);

    // ---- level 1 ----
    hipMemsetAsync(x1, 0, (size_t)U1 * 128 * sizeof(float), stream);
    scat(x1, feats1, lat1, N1, 128);
    scat(x1, t2c, up1, G2n, 128);

    conv(x1, w_out1, m_u1, Mu1, U1, 128, 7, 128, smallTab, out1);
    bnelu(out1, bn_out1, U1, 128);
    tconv(x1, wt1, t1, U1, 128, 7, 64);
    bnelu(t1, bn_up1a, G1n, 64);
    conv(t1, wu1, m_g1, Mg1, G1n, 64, 6, 64, tab_g1, t1c);
    bnelu(t1c, bn_up1b, G1n, 64);

    // ---- level 0 ----
    hipMemsetAsync(x0, 0, (size_t)U0 * 64 * sizeof(float), stream);
    scat(x0, feats0, lat0, N0, 64);
    scat(x0, t1c, up0, G1n, 64);

    conv(x0, w_out0, m_u0, Mu0, U0, 64, 6, 128, tab_u0, out0);
    bnelu(out0, bn_out0, U0, 128);
}

// Round 3
// 1313.374 us; speedup vs baseline: 4.5778x; 2.2765x over previous
//
#include <hip/hip_runtime.h>

typedef __bf16 bf16x8 __attribute__((ext_vector_type(8)));
typedef float  f32x4  __attribute__((ext_vector_type(4)));

__device__ __forceinline__ float b2f(unsigned short u) {
    union { unsigned int i; float f; } v; v.i = ((unsigned int)u) << 16; return v.f;
}
__device__ __forceinline__ unsigned short f2b(float f) {
    union { float f; unsigned int i; } v; v.f = f;
    unsigned int u = v.i;
    return (unsigned short)((u + 0x7fffu + ((u >> 16) & 1u)) >> 16);
}

// ---------------- tap table build ----------------
__global__ void table_init(int* __restrict__ tab, int n)
{
    int idx = blockIdx.x * blockDim.x + threadIdx.x;
    if (idx >= n * 27) return;
    tab[idx] = ((idx % 27) == 13) ? (idx / 27) : -1;
}

__global__ void table_fill(int* __restrict__ tab, const int* __restrict__ map, int M, int n)
{
    int tid = blockIdx.x * blockDim.x + threadIdx.x;
    if (tid >= 26 * M) return;
    int j = tid / M, q = tid - j * M;
    int om = map[(26 + j) * M + q];
    if (om < n) {
        int k = (j < 13) ? j : j + 1;
        tab[om * 27 + k] = map[j * M + q];
    }
}

// ---------------- weight pack: W[j][k][cout] f32 -> B-fragment order bf16 ----------------
// P[((j*KC+kc)*4+quad)*Cout*8 + cout*8 + jj] = bf16(W[j][kc*32+quad*8+jj][cout])
__global__ void pack_w(const float* __restrict__ W, unsigned short* __restrict__ P,
                       int total, int log2Cout, int log2KC)
{
    int tid = blockIdx.x * blockDim.x + threadIdx.x;
    if (tid >= total) return;
    int jj   = tid & 7;
    int cout = (tid >> 3) & ((1 << log2Cout) - 1);
    int rest = tid >> (3 + log2Cout);
    int quad = rest & 3;
    int kj   = rest >> 2;
    int kc   = kj & ((1 << log2KC) - 1);
    int j    = kj >> log2KC;
    int Cin  = (1 << log2KC) * 32;
    int Cout = 1 << log2Cout;
    P[tid] = f2b(W[((size_t)j * Cin + kc * 32 + quad * 8 + jj) * Cout + cout]);
}

__global__ void cast_bf16(const float* __restrict__ X, unsigned short* __restrict__ Y, int nElem)
{
    int tid = blockIdx.x * blockDim.x + threadIdx.x;
    if (tid < nElem) Y[tid] = f2b(X[tid]);
}

// ---------------- MFMA output-centric sparse conv ----------------
// 256 threads = 4 waves, 16 output rows per block, Cout = 64*T (wave wv owns tiles wv*T..).
template<int T, bool OUTBF16>
__global__ __launch_bounds__(256) void conv_mfma(
    const unsigned short* __restrict__ Xb, const unsigned short* __restrict__ P,
    const int* __restrict__ tab, void* __restrict__ OutV, int n, int Cin, int KC)
{
    const int Cout = 64 * T;
    __shared__ int tps[16 * 27];
    __shared__ int vld[27];
    const int t = threadIdx.x, lane = t & 63, wv = t >> 6;
    const int m = lane & 15, quad = lane >> 4;
    const int r0 = blockIdx.x * 16;
    int rows = n - r0; if (rows > 16) rows = 16;

    for (int e = t; e < 16 * 27; e += 256)
        tps[e] = (e < rows * 27) ? tab[(size_t)r0 * 27 + e] : -1;
    __syncthreads();
    if (t < 27) {
        int v = 0;
        for (int r = 0; r < 16; r++) v |= (tps[r * 27 + t] >= 0) ? 1 : 0;
        vld[t] = v;
    }
    __syncthreads();

    f32x4 acc[T];
    #pragma unroll
    for (int c = 0; c < T; c++) acc[c] = f32x4{0.f, 0.f, 0.f, 0.f};

    for (int j = 0; j < 27; j++) {
        if (!vld[j]) continue;
        int in = tps[m * 27 + j];
        for (int kc = 0; kc < KC; kc++) {
            bf16x8 a{};
            if (in >= 0)
                a = *reinterpret_cast<const bf16x8*>(Xb + (size_t)in * Cin + kc * 32 + quad * 8);
            const unsigned short* bp = P + ((size_t)((j * KC + kc) * 4 + quad) * Cout + wv * (T * 16)) * 8;
            #pragma unroll
            for (int c = 0; c < T; c++) {
                bf16x8 b = *reinterpret_cast<const bf16x8*>(bp + (c * 16 + m) * 8);
                acc[c] = __builtin_amdgcn_mfma_f32_16x16x32_bf16(a, b, acc[c], 0, 0, 0);
            }
        }
    }

    #pragma unroll
    for (int c = 0; c < T; c++) {
        int cout = (wv * T + c) * 16 + m;
        #pragma unroll
        for (int reg = 0; reg < 4; reg++) {
            int r = quad * 4 + reg;
            if (r < rows) {
                size_t off = (size_t)(r0 + r) * Cout + cout;
                if (OUTBF16) ((unsigned short*)OutV)[off] = f2b(acc[c][reg]);
                else         ((float*)OutV)[off] = acc[c][reg];
            }
        }
    }
}

// ---------------- MFMA transpose conv: 8 children per row, A held in regs ----------------
template<int KC, int T>
__global__ __launch_bounds__(256) void tconv_mfma(
    const unsigned short* __restrict__ Xb, const unsigned short* __restrict__ P,
    unsigned short* __restrict__ Out, int n)
{
    const int Cin = KC * 32, Cout = 64 * T;
    const int t = threadIdx.x, lane = t & 63, wv = t >> 6;
    const int m = lane & 15, quad = lane >> 4;
    const int r0 = blockIdx.x * 16;
    int rows = n - r0; if (rows > 16) rows = 16;

    bf16x8 a[KC];
    #pragma unroll
    for (int kc = 0; kc < KC; kc++) {
        a[kc] = bf16x8{};
        if (m < rows)
            a[kc] = *reinterpret_cast<const bf16x8*>(Xb + (size_t)(r0 + m) * Cin + kc * 32 + quad * 8);
    }

    for (int o = 0; o < 8; o++) {
        f32x4 acc[T];
        #pragma unroll
        for (int c = 0; c < T; c++) acc[c] = f32x4{0.f, 0.f, 0.f, 0.f};
        #pragma unroll
        for (int kc = 0; kc < KC; kc++) {
            const unsigned short* bp = P + ((size_t)((o * KC + kc) * 4 + quad) * Cout + wv * (T * 16)) * 8;
            #pragma unroll
            for (int c = 0; c < T; c++) {
                bf16x8 b = *reinterpret_cast<const bf16x8*>(bp + (c * 16 + m) * 8);
                acc[c] = __builtin_amdgcn_mfma_f32_16x16x32_bf16(a[kc], b, acc[c], 0, 0, 0);
            }
        }
        #pragma unroll
        for (int c = 0; c < T; c++) {
            int cout = (wv * T + c) * 16 + m;
            #pragma unroll
            for (int reg = 0; reg < 4; reg++) {
                int r = quad * 4 + reg;
                if (r < rows)
                    Out[((size_t)o * n + r0 + r) * Cout + cout] = f2b(acc[c][reg]);
            }
        }
    }
}

// ---------------- misc ----------------
__global__ void scatter_add_f32(float* __restrict__ dst, const float* __restrict__ src,
                                const int* __restrict__ idx, long total, int C)
{
    long tid = (long)blockIdx.x * blockDim.x + threadIdx.x;
    if (tid >= total) return;
    long r = tid / C;
    int  c = (int)(tid - r * C);
    dst[(long)idx[r] * C + c] += src[tid];
}

__global__ void scatter_add_b16(float* __restrict__ dst, const unsigned short* __restrict__ src,
                                const int* __restrict__ idx, long total, int C)
{
    long tid = (long)blockIdx.x * blockDim.x + threadIdx.x;
    if (tid >= total) return;
    long r = tid / C;
    int  c = (int)(tid - r * C);
    dst[(long)idx[r] * C + c] += b2f(src[tid]);
}

template<bool BF16>
__global__ void bn_stats_k(const void* __restrict__ Xv, float* __restrict__ stats,
                           int n, int C, int rowsPerBlock)
{
    const int t = threadIdx.x;
    const int c = t & (C - 1);
    const int sub = t / C;
    const int nsub = 256 / C;
    int r0 = blockIdx.x * rowsPerBlock + sub;
    int r1 = blockIdx.x * rowsPerBlock + rowsPerBlock;
    if (r1 > n) r1 = n;
    float s = 0.f, ss = 0.f;
    for (int r = r0; r < r1; r += nsub) {
        float v = BF16 ? b2f(((const unsigned short*)Xv)[(long)r * C + c])
                       : ((const float*)Xv)[(long)r * C + c];
        s += v; ss += v * v;
    }
    __shared__ float bs[256];
    __shared__ float bq[256];
    bs[t] = s; bq[t] = ss;
    __syncthreads();
    if (sub == 0) {
        for (int k = 1; k < nsub; k++) { s += bs[k * C + c]; ss += bq[k * C + c]; }
        atomicAdd(&stats[c], s);
        atomicAdd(&stats[C + c], ss);
    }
}

template<bool BF16>
__global__ void bn_apply_k(void* __restrict__ Xv, const float* __restrict__ stats,
                           const float* __restrict__ gb, long total, int C, float invn)
{
    long tid = (long)blockIdx.x * blockDim.x + threadIdx.x;
    if (tid >= total) return;
    int c = (int)(tid & (C - 1));
    float mu  = stats[c] * invn;
    float var = stats[C + c] * invn - mu * mu;
    float sc  = gb[c] * rsqrtf(var + 1e-5f);
    float x   = BF16 ? b2f(((unsigned short*)Xv)[tid]) : ((float*)Xv)[tid];
    float v   = (x - mu) * sc + gb[C + c];
    v = (v > 0.f) ? v : expm1f(v);
    if (BF16) ((unsigned short*)Xv)[tid] = f2b(v);
    else      ((float*)Xv)[tid] = v;
}

extern "C" void kernel_launch(void* const* d_in, const int* in_sizes, int n_in,
                              void* d_out, int out_size, void* d_ws, size_t ws_size,
                              hipStream_t stream)
{
    const float* feats0  = (const float*)d_in[0];
    const float* feats1  = (const float*)d_in[1];
    const float* feats2  = (const float*)d_in[2];
    const float* w_out0  = (const float*)d_in[3];
    const float* w_out1  = (const float*)d_in[4];
    const float* w_out2  = (const float*)d_in[5];
    const float* wt2     = (const float*)d_in[6];
    const float* wu2     = (const float*)d_in[7];
    const float* wt1     = (const float*)d_in[8];
    const float* wu1     = (const float*)d_in[9];
    const float* bn_out0 = (const float*)d_in[10];
    const float* bn_out1 = (const float*)d_in[11];
    const float* bn_out2 = (const float*)d_in[12];
    const float* bn_up2a = (const float*)d_in[13];
    const float* bn_up2b = (const float*)d_in[14];
    const float* bn_up1a = (const float*)d_in[15];
    const float* bn_up1b = (const float*)d_in[16];
    const int* m_c2 = (const int*)d_in[19];
    const int* m_g2 = (const int*)d_in[20];
    const int* m_u1 = (const int*)d_in[21];
    const int* m_g1 = (const int*)d_in[22];
    const int* m_u0 = (const int*)d_in[23];
    const int* lat1 = (const int*)d_in[24];
    const int* up1  = (const int*)d_in[25];
    const int* lat0 = (const int*)d_in[26];
    const int* up0  = (const int*)d_in[27];

    const int N0  = in_sizes[0] / 64;
    const int N1  = in_sizes[1] / 128;
    const int N2  = in_sizes[2] / 256;
    const int U1  = in_sizes[17] / 128;
    const int U0  = in_sizes[18] / 64;
    const int G2n = in_sizes[25];        // 8*N2
    const int G1n = in_sizes[27];        // 8*U1
    const int Mc2 = in_sizes[19] / 52;
    const int Mg2 = in_sizes[20] / 52;
    const int Mu1 = in_sizes[21] / 52;
    const int Mg1 = in_sizes[22] / 52;
    const int Mu0 = in_sizes[23] / 52;

    float* out0 = (float*)d_out;
    float* out1 = out0 + (size_t)U0 * 128;
    float* out2 = out1 + (size_t)U1 * 128;

    // ---- workspace (256B-aligned bump allocator) ----
    char* wp = (char*)d_ws;
    auto alloc = [&](size_t bytes) -> char* {
        char* r = wp; wp += (bytes + 255) & ~(size_t)255; return r;
    };
    float*          x0   = (float*)alloc((size_t)U0 * 64 * 4);   // tab_g1 aliases (built before x0 written)
    unsigned short* t1   = (unsigned short*)alloc((size_t)G1n * 64 * 2);  // tab_u0 aliases t1|t1c (both dead)
    unsigned short* t1c  = (unsigned short*)alloc((size_t)G1n * 64 * 2);
    unsigned short* t2   = (unsigned short*)alloc((size_t)G2n * 128 * 2);
    unsigned short* t2c  = (unsigned short*)alloc((size_t)G2n * 128 * 2);
    float*          x1   = (float*)alloc((size_t)U1 * 128 * 4);
    unsigned short* x1b  = (unsigned short*)alloc((size_t)U1 * 128 * 2);
    unsigned short* x0b  = (unsigned short*)alloc((size_t)U0 * 64 * 2);
    unsigned short* f2bb = (unsigned short*)alloc((size_t)N2 * 256 * 2);
    unsigned short* pc2  = (unsigned short*)alloc((size_t)27 * 256 * 128 * 2);
    unsigned short* pt2  = (unsigned short*)alloc((size_t)8  * 256 * 128 * 2);
    unsigned short* pg2  = (unsigned short*)alloc((size_t)27 * 128 * 128 * 2);
    unsigned short* pu1  = (unsigned short*)alloc((size_t)27 * 128 * 128 * 2);
    unsigned short* pt1  = (unsigned short*)alloc((size_t)8  * 128 * 64  * 2);
    unsigned short* pg1  = (unsigned short*)alloc((size_t)27 * 64  * 64  * 2);
    unsigned short* pu0  = (unsigned short*)alloc((size_t)27 * 64  * 128 * 2);
    int maxSmall = (U1 > G2n) ? U1 : G2n;
    int*   smallTab = (int*)alloc((size_t)maxSmall * 27 * 4);
    float* stats    = (float*)alloc(1024);
    int* tab_g1 = (int*)x0;   // G1n*27*4  <= U0*64*4 since U0 >= G1n
    int* tab_u0 = (int*)t1;   // U0*27*4   <= 2*G1n*64*2 region (t1+t1c)

    auto packW = [&](const float* W, unsigned short* P, int taps, int l2co, int l2kc) {
        int total = taps * ((1 << l2kc) * 32) * (1 << l2co);
        pack_w<<<dim3((total + 255) / 256), dim3(256), 0, stream>>>(W, P, total, l2co, l2kc);
    };
    auto cast = [&](const float* X, unsigned short* Y, long nElem) {
        cast_bf16<<<dim3((int)((nElem + 255) / 256)), dim3(256), 0, stream>>>(X, Y, (int)nElem);
    };
    auto buildTab = [&](int* tab, const int* map, int M, int n) {
        table_init<<<dim3((n * 27 + 255) / 256), dim3(256), 0, stream>>>(tab, n);
        table_fill<<<dim3((26 * M + 255) / 256), dim3(256), 0, stream>>>(tab, map, M, n);
    };
    auto conv = [&](const unsigned short* Xb, const unsigned short* P, const int* tab,
                    void* Out, int n, int Cin, int Cout, bool outbf16) {
        int blocks = (n + 15) / 16, KC = Cin / 32;
        if (Cout == 128) {
            if (outbf16) conv_mfma<2, true ><<<dim3(blocks), dim3(256), 0, stream>>>(Xb, P, tab, Out, n, Cin, KC);
            else         conv_mfma<2, false><<<dim3(blocks), dim3(256), 0, stream>>>(Xb, P, tab, Out, n, Cin, KC);
        } else {
            if (outbf16) conv_mfma<1, true ><<<dim3(blocks), dim3(256), 0, stream>>>(Xb, P, tab, Out, n, Cin, KC);
            else         conv_mfma<1, false><<<dim3(blocks), dim3(256), 0, stream>>>(Xb, P, tab, Out, n, Cin, KC);
        }
    };
    auto bnelu = [&](void* X, const float* gb, int n, int C, bool bf16) {
        hipMemsetAsync(stats, 0, 2 * C * sizeof(float), stream);
        const int rpb = 512;
        long total = (long)n * C;
        if (bf16) {
            bn_stats_k<true ><<<dim3((n + rpb - 1) / rpb), dim3(256), 0, stream>>>(X, stats, n, C, rpb);
            bn_apply_k<true ><<<dim3((int)((total + 255) / 256)), dim3(256), 0, stream>>>(X, stats, gb, total, C, 1.0f / n);
        } else {
            bn_stats_k<false><<<dim3((n + rpb - 1) / rpb), dim3(256), 0, stream>>>(X, stats, n, C, rpb);
            bn_apply_k<false><<<dim3((int)((total + 255) / 256)), dim3(256), 0, stream>>>(X, stats, gb, total, C, 1.0f / n);
        }
    };

    // ---- weight packs + input cast ----
    cast(feats2, f2bb, (long)N2 * 256);
    packW(w_out2, pc2, 27, 7, 3);
    packW(wt2,    pt2,  8, 7, 3);
    packW(wu2,    pg2, 27, 7, 2);
    packW(w_out1, pu1, 27, 7, 2);
    packW(wt1,    pt1,  8, 6, 2);
    packW(wu1,    pg1, 27, 6, 1);
    packW(w_out0, pu0, 27, 7, 1);

    // ---- level 2 ----
    buildTab(smallTab, m_c2, Mc2, N2);
    conv(f2bb, pc2, smallTab, out2, N2, 256, 128, false);
    bnelu(out2, bn_out2, N2, 128, false);
    tconv_mfma<8, 2><<<dim3((N2 + 15) / 16), dim3(256), 0, stream>>>(f2bb, pt2, t2, N2);
    bnelu(t2, bn_up2a, G2n, 128, true);
    buildTab(smallTab, m_g2, Mg2, G2n);
    conv(t2, pg2, smallTab, t2c, G2n, 128, 128, true);
    bnelu(t2c, bn_up2b, G2n, 128, true);

    // ---- level 1 ----
    hipMemsetAsync(x1, 0, (size_t)U1 * 128 * sizeof(float), stream);
    {
        long tot = (long)N1 * 128;
        scatter_add_f32<<<dim3((int)((tot + 255) / 256)), dim3(256), 0, stream>>>(x1, feats1, lat1, tot, 128);
        tot = (long)G2n * 128;
        scatter_add_b16<<<dim3((int)((tot + 255) / 256)), dim3(256), 0, stream>>>(x1, t2c, up1, tot, 128);
    }
    cast(x1, x1b, (long)U1 * 128);
    buildTab(smallTab, m_u1, Mu1, U1);
    conv(x1b, pu1, smallTab, out1, U1, 128, 128, false);
    bnelu(out1, bn_out1, U1, 128, false);
    tconv_mfma<4, 1><<<dim3((U1 + 15) / 16), dim3(256), 0, stream>>>(x1b, pt1, t1, U1);
    bnelu(t1, bn_up1a, G1n, 64, true);
    buildTab(tab_g1, m_g1, Mg1, G1n);
    conv(t1, pg1, tab_g1, t1c, G1n, 64, 64, true);
    bnelu(t1c, bn_up1b, G1n, 64, true);

    // ---- level 0 ----
    hipMemsetAsync(x0, 0, (size_t)U0 * 64 * sizeof(float), stream);
    {
        long tot = (long)N0 * 64;
        scatter_add_f32<<<dim3((int)((tot + 255) / 256)), dim3(256), 0, stream>>>(x0, feats0, lat0, tot, 64);
        tot = (long)G1n * 64;
        scatter_add_b16<<<dim3((int)((tot + 255) / 256)), dim3(256), 0, stream>>>(x0, t1c, up0, tot, 64);
    }
    buildTab(tab_u0, m_u0, Mu0, U0);
    cast(x0, x0b, (long)U0 * 64);
    conv(x0b, pu0, tab_u0, out0, U0, 64, 128, false);
    bnelu(out0, bn_out0, U0, 128, false);
}